// Round 10
// baseline (378.758 us; speedup 1.0000x reference)
//
#include <hip/hip_runtime.h>

typedef __attribute__((ext_vector_type(4))) float f32x4;
typedef __attribute__((ext_vector_type(2))) long i64x2;

// ---------- exact fp8 e4m3fn ENCODE (RNE, saturating), matching ml_dtypes ----------
__device__ __forceinline__ unsigned char enc_e4m3(float y) {
    unsigned int u = __float_as_uint(y);
    unsigned int s = (u >> 31) << 7;
    unsigned int a = u & 0x7fffffffu;
    if (a >= 0x3C800000u) {                       // |y| >= 2^-6: normal e4m3
        unsigned int r = a + 0x7FFFFu + ((a >> 20) & 1u);   // RNE to 3 mant bits
        r &= 0xFFF00000u;
        if (r > 0x43E00000u) r = 0x43E00000u;     // saturate 448
        unsigned int e = (r >> 23) - 120u;
        return (unsigned char)(s | (e << 3) | ((r >> 20) & 7u));
    } else {                                      // subnormal: grid 2^-9
        int m = (int)rintf(__uint_as_float(a) * 512.0f);
        return (unsigned char)(s | (unsigned)m);
    }
}

__device__ __forceinline__ unsigned short f32_to_bf16_bits(float f) {
    unsigned int u = __float_as_uint(f);
    u += 0x7FFFu + ((u >> 16) & 1u);
    return (unsigned short)(u >> 16);
}

// interleaved column within a 64-K block: chunk kh (16B) holds k={kh*8..+7} U {32+kh*8..+7}
__device__ __forceinline__ int ilv_col(int c) {   // c in [0,64)
    return ((c & 31) >> 3) * 16 + (c >> 5) * 8 + (c & 7);
}

// ---------- quantize x: per-row 1x64 tiles -> fp8 bytes (interleaved) + xsT[t][i] ----------
__global__ __launch_bounds__(256) void quant_x_kernel(const float* __restrict__ x,
                                                      unsigned char* __restrict__ xq,
                                                      float* __restrict__ xsT,
                                                      long long n4, int K, int M) {
    long long g = (long long)blockIdx.x * 256 + threadIdx.x;
    if (g >= n4) return;
    f32x4 v = ((const f32x4*)x)[g];
    float a = fmaxf(fmaxf(fabsf(v.x), fabsf(v.y)), fmaxf(fabsf(v.z), fabsf(v.w)));
    a = fmaxf(a, __shfl_xor(a, 1));
    a = fmaxf(a, __shfl_xor(a, 2));
    a = fmaxf(a, __shfl_xor(a, 4));
    a = fmaxf(a, __shfl_xor(a, 8));
    float scale = fmaxf(a, 1e-12f) / 448.0f;
    long long flat = g * 4;
    int row = (int)(flat / K);
    int rem = (int)(flat % K);
    int kb = rem >> 6, c0 = rem & 63;
    uchar4 o;
    o.x = enc_e4m3(v.x / scale);
    o.y = enc_e4m3(v.y / scale);
    o.z = enc_e4m3(v.z / scale);
    o.w = enc_e4m3(v.w / scale);
    *(uchar4*)(xq + (size_t)row * K + kb * 64 + ilv_col(c0)) = o;
    if ((c0 & 63) == 0)
        xsT[(size_t)kb * M + row] = scale;
}

// ---------- quantize w: 64x64 blocks -> fp8 (interleaved) + ws[nb][kb] ----------
__global__ __launch_bounds__(256) void quant_w_kernel(const float* __restrict__ w,
                                                      unsigned char* __restrict__ wq,
                                                      float* __restrict__ ws,
                                                      int N, int K) {
    const int nb = blockIdx.y, kb = blockIdx.x;
    const int KT = K >> 6;
    const int t = threadIdx.x;
    const int rgrp = t >> 4;
    const int cchk = t & 15;
    f32x4 v[4];
    float a = 0.0f;
#pragma unroll
    for (int i = 0; i < 4; ++i) {
        int row = nb * 64 + rgrp + i * 16;
        v[i] = *(const f32x4*)(w + (size_t)row * K + kb * 64 + cchk * 4);
        a = fmaxf(a, fmaxf(fmaxf(fabsf(v[i].x), fabsf(v[i].y)),
                           fmaxf(fabsf(v[i].z), fabsf(v[i].w))));
    }
#pragma unroll
    for (int off = 1; off < 64; off <<= 1) a = fmaxf(a, __shfl_xor(a, off));
    __shared__ float sm[4];
    if ((t & 63) == 0) sm[t >> 6] = a;
    __syncthreads();
    a = fmaxf(fmaxf(sm[0], sm[1]), fmaxf(sm[2], sm[3]));
    float scale = fmaxf(a, 1e-12f) / 448.0f;
    const int oc = ilv_col(cchk * 4);
#pragma unroll
    for (int i = 0; i < 4; ++i) {
        int row = nb * 64 + rgrp + i * 16;
        uchar4 o;
        o.x = enc_e4m3(v[i].x / scale);
        o.y = enc_e4m3(v[i].y / scale);
        o.z = enc_e4m3(v[i].z / scale);
        o.w = enc_e4m3(v[i].w / scale);
        *(uchar4*)(wq + (size_t)row * K + kb * 64 + oc) = o;
    }
    if (t == 0) ws[(size_t)nb * KT + kb] = scale;
}

// ---------- 256x128 block-scaled fp8 GEMM, 2 blocks/CU for pipe overlap ----------
// Wave-tile 64x64 -> macc 64 regs; total ~125 regs -> 4 waves/SIMD -> 2 blocks/CU.
// LDS swizzle (R9-verified zero-conflict): chunk c of row r at slot c ^ ((r>>1)&3).
#define GLDS(srcp, ldsp) __builtin_amdgcn_global_load_lds( \
    (__attribute__((address_space(1))) void*)(srcp),       \
    (__attribute__((address_space(3))) void*)(ldsp), 16, 0, 0)

#define MFMA8(aa, bb, cc) __builtin_amdgcn_mfma_f32_16x16x32_fp8_fp8(aa, bb, cc, 0, 0, 0)

__global__ __launch_bounds__(512, 4) void gemm_fp8(const unsigned char* __restrict__ Aq,
                                                   const unsigned char* __restrict__ Bq,
                                                   const float* __restrict__ xsT,
                                                   const float* __restrict__ wss,
                                                   const float* __restrict__ bias,
                                                   float* __restrict__ C,
                                                   int M, int N, int K) {
    __shared__ unsigned char Al[2][16384];    // 256 rows x 64B
    __shared__ unsigned char Bl[2][8192];     // 128 rows x 64B
    const int tid = threadIdx.x;
    const int wid = tid >> 6;
    const int lane = tid & 63;
    const int wm = wid >> 1, wn = wid & 1;    // 4 x 2 waves, wave-tile 64x64
    const int l15 = lane & 15;
    const int KT = K >> 6, NT = KT;

    // XCD-aware bijective swizzle (nwg = 1024, %8==0)
    const int nbx = N >> 7;                   // 32
    const int nwg = (M >> 8) * nbx;           // 1024
    const int bid = blockIdx.x;
    const int swz = (bid & 7) * (nwg >> 3) + (bid >> 3);
    const int tm = swz / nbx, tn = swz % nbx;

    const unsigned char* gA = Aq + (size_t)tm * 256 * K;
    const unsigned char* gB = Bq + (size_t)tn * 128 * K;

    // staging source col swizzle: chunk = (lane&3) ^ ((lane>>3)&3)  [f(row)=(row>>1)&3]
    const int gswz = (((lane & 3) ^ ((lane >> 3) & 3)) << 4);
    // ds_read col swizzle: slot = kh ^ ((l15>>1)&3)
    const int cSwz = (((lane >> 4) ^ ((lane >> 1) & 3)) << 4);

    const int iRow = tm * 256 + wm * 64 + l15;    // X-row base for scales/output
    const int jbw  = tn * 2 + wn;                 // W 64-block index

    f32x4 macc[4][4];                              // [nw][mx]
#pragma unroll
    for (int n = 0; n < 4; ++n)
#pragma unroll
        for (int m = 0; m < 4; ++m) macc[n][m] = (f32x4){0.f, 0.f, 0.f, 0.f};

    i64x2 xf[4], wf[4];
    float xsA[4], xsB[4], wsA = 0.f, wsB = 0.f;
    const f32x4 z4 = (f32x4){0.f, 0.f, 0.f, 0.f};

    auto STG = [&](int t, int bufn) {              // 3 GLDS/wave (2 A segs + 1 B seg)
#pragma unroll
        for (int i = 0; i < 2; ++i) {
            int seg = wid * 2 + i;                 // 16 A segs x 1KB (16 rows)
            int row = seg * 16 + (lane >> 2);
            GLDS(gA + (size_t)row * K + (size_t)t * 64 + gswz, (char*)&Al[bufn][0] + seg * 1024);
        }
        {
            int seg = wid;                         // 8 B segs
            int row = seg * 16 + (lane >> 2);
            GLDS(gB + (size_t)row * K + (size_t)t * 64 + gswz, (char*)&Bl[bufn][0] + seg * 1024);
        }
    };

    const unsigned char* pAb[2] = {&Al[0][0] + (wm * 64 + l15) * 64 + cSwz,
                                   &Al[1][0] + (wm * 64 + l15) * 64 + cSwz};
    const unsigned char* pBb[2] = {&Bl[0][0] + (wn * 64 + l15) * 64 + cSwz,
                                   &Bl[1][0] + (wn * 64 + l15) * 64 + cSwz};

    // cluster: 4 mx x 2 nw fragments over K=64, rescale fmacs in same sched region
    auto CL = [&](int no, const float (&xs)[4], float wsv) {
#pragma unroll
        for (int mi = 0; mi < 4; ++mi) {
            float s = xs[mi] * wsv;
#pragma unroll
            for (int ni = 0; ni < 2; ++ni) {
                f32x4 p = MFMA8(wf[no + ni].x, xf[mi].x, z4);
                p = MFMA8(wf[no + ni].y, xf[mi].y, p);
                macc[no + ni][mi] += p * s;
            }
        }
    };

    // prologue: stage tile0 -> buf0, scales for tile0
    STG(0, 0);
#pragma unroll
    for (int m = 0; m < 4; ++m) xsA[m] = xsT[iRow + m * 16];
    wsA = wss[(size_t)jbw * KT];
    asm volatile("s_waitcnt vmcnt(0)" ::: "memory");
    asm volatile("s_barrier" ::: "memory");
#pragma unroll
    for (int m = 0; m < 4; ++m) xf[m] = *(const i64x2*)(pAb[0] + m * 1024);
#pragma unroll
    for (int n = 0; n < 2; ++n) wf[n] = *(const i64x2*)(pBb[0] + n * 1024);

    auto TILE = [&](int buf, int tnx, const float (&xsC)[4], float wsC,
                    float (&xsN)[4], float& wsN) {
        const unsigned char* pB  = pBb[buf];
        const unsigned char* pAn = pAb[buf ^ 1];
        const unsigned char* pBn = pBb[buf ^ 1];

        // ph0: stage next tile + prefetch its scales; read wf2-3; cluster n0-1
        STG(tnx, buf ^ 1);
#pragma unroll
        for (int m = 0; m < 4; ++m) xsN[m] = xsT[(size_t)tnx * M + iRow + m * 16];
        wsN = wss[(size_t)jbw * KT + tnx];
#pragma unroll
        for (int n = 0; n < 2; ++n) wf[n + 2] = *(const i64x2*)(pB + (n + 2) * 1024);
        asm volatile("s_waitcnt lgkmcnt(2)" ::: "memory");
        __builtin_amdgcn_sched_barrier(0);
        __builtin_amdgcn_s_setprio(1);
        CL(0, xsC, wsC);
        __builtin_amdgcn_s_setprio(0);

        // ph1: cluster n2-3
        asm volatile("s_waitcnt lgkmcnt(0)" ::: "memory");
        __builtin_amdgcn_sched_barrier(0);
        __builtin_amdgcn_s_setprio(1);
        CL(2, xsC, wsC);
        __builtin_amdgcn_s_setprio(0);

        // tile boundary + tail-read next tile's first fragments
        asm volatile("s_waitcnt vmcnt(0)" ::: "memory");   // next buf fully staged
        asm volatile("s_barrier" ::: "memory");            // join all waves
#pragma unroll
        for (int m = 0; m < 4; ++m) xf[m] = *(const i64x2*)(pAn + m * 1024);
#pragma unroll
        for (int n = 0; n < 2; ++n) wf[n] = *(const i64x2*)(pBn + n * 1024);
    };

    for (int t = 0; t < NT; t += 2) {
        int t1 = t + 1;
        int t2 = (t + 2 < NT) ? (t + 2) : 0;     // wrap: redundant but uniform
        TILE(0, t1, xsA, wsA, xsB, wsB);
        TILE(1, t2, xsB, wsB, xsA, wsA);
    }

    // epilogue: D col = lane&15 -> X-row; D rows -> W-cols (contiguous f32x4)
    const int jc0 = tn * 128 + wn * 64 + (lane >> 4) * 4;
#pragma unroll
    for (int ni = 0; ni < 4; ++ni) {
        f32x4 bv = *(const f32x4*)(bias + jc0 + ni * 16);
#pragma unroll
        for (int mi = 0; mi < 4; ++mi) {
            f32x4 vo;
#pragma unroll
            for (int j = 0; j < 4; ++j) {
                unsigned short b = f32_to_bf16_bits(macc[ni][mi][j]);
                vo[j] = __uint_as_float(((unsigned int)b) << 16) + bv[j];
            }
            *(f32x4*)(C + (size_t)(iRow + mi * 16) * N + jc0 + ni * 16) = vo;
        }
    }
}

extern "C" void kernel_launch(void* const* d_in, const int* in_sizes, int n_in,
                              void* d_out, int out_size, void* d_ws, size_t ws_size,
                              hipStream_t stream) {
    const float* x    = (const float*)d_in[0];
    const float* w    = (const float*)d_in[1];
    const float* bias = (const float*)d_in[2];
    float* out = (float*)d_out;

    const int N = in_sizes[2];
    const long long KL = (long long)in_sizes[1] / N;
    const int K = (int)KL;
    const int M = (int)((long long)in_sizes[0] / KL);
    const int KT = K / 64;

    unsigned char* xq = (unsigned char*)d_ws;                       // M*K fp8
    unsigned char* wq = xq + (size_t)M * K;                         // N*K fp8
    float* xsT = (float*)(wq + (size_t)N * K);                      // KT*M f32
    float* wss = xsT + (size_t)KT * M;                              // (N/64)*KT f32

    long long n4 = (long long)M * K / 4;
    quant_x_kernel<<<(unsigned)((n4 + 255) / 256), 256, 0, stream>>>(x, xq, xsT, n4, K, M);

    dim3 gw(K / 64, N / 64);
    quant_w_kernel<<<gw, 256, 0, stream>>>(w, wq, wss, N, K);

    const int nwg = (M / 256) * (N / 128);
    gemm_fp8<<<nwg, 512, 0, stream>>>(xq, wq, xsT, wss, bias, out, M, N, K);
}

// Round 11
// 272.430 us; speedup vs baseline: 1.3903x; 1.3903x over previous
//
#include <hip/hip_runtime.h>

typedef __attribute__((ext_vector_type(4))) float f32x4;
typedef __attribute__((ext_vector_type(16))) float f32x16;
typedef __attribute__((ext_vector_type(4))) int i32x4;
typedef __attribute__((ext_vector_type(8))) int i32x8;

// ---------- exact fp8 e4m3fn ENCODE (RNE, saturating), matching ml_dtypes ----------
__device__ __forceinline__ unsigned char enc_e4m3(float y) {
    unsigned int u = __float_as_uint(y);
    unsigned int s = (u >> 31) << 7;
    unsigned int a = u & 0x7fffffffu;
    if (a >= 0x3C800000u) {                       // |y| >= 2^-6: normal e4m3
        unsigned int r = a + 0x7FFFFu + ((a >> 20) & 1u);   // RNE to 3 mant bits
        r &= 0xFFF00000u;
        if (r > 0x43E00000u) r = 0x43E00000u;     // saturate 448
        unsigned int e = (r >> 23) - 120u;
        return (unsigned char)(s | (e << 3) | ((r >> 20) & 7u));
    } else {                                      // subnormal: grid 2^-9
        int m = (int)rintf(__uint_as_float(a) * 512.0f);
        return (unsigned char)(s | (unsigned)m);
    }
}

__device__ __forceinline__ unsigned short f32_to_bf16_bits(float f) {
    unsigned int u = __float_as_uint(f);
    u += 0x7FFFu + ((u >> 16) & 1u);
    return (unsigned short)(u >> 16);
}

// ---------- quantize x: per-row 1x64 tiles -> fp8 (plain row-major) + xsT[t][i] ----------
__global__ __launch_bounds__(256) void quant_x_kernel(const float* __restrict__ x,
                                                      unsigned char* __restrict__ xq,
                                                      float* __restrict__ xsT,
                                                      long long n4, int K, int M) {
    long long g = (long long)blockIdx.x * 256 + threadIdx.x;
    if (g >= n4) return;
    f32x4 v = ((const f32x4*)x)[g];
    float a = fmaxf(fmaxf(fabsf(v.x), fabsf(v.y)), fmaxf(fabsf(v.z), fabsf(v.w)));
    a = fmaxf(a, __shfl_xor(a, 1));
    a = fmaxf(a, __shfl_xor(a, 2));
    a = fmaxf(a, __shfl_xor(a, 4));
    a = fmaxf(a, __shfl_xor(a, 8));
    float scale = fmaxf(a, 1e-12f) / 448.0f;
    long long flat = g * 4;
    uchar4 o;
    o.x = enc_e4m3(v.x / scale);
    o.y = enc_e4m3(v.y / scale);
    o.z = enc_e4m3(v.z / scale);
    o.w = enc_e4m3(v.w / scale);
    *(uchar4*)(xq + flat) = o;
    int row = (int)(flat / K);
    int rem = (int)(flat % K);
    if ((rem & 63) == 0)
        xsT[(size_t)(rem >> 6) * M + row] = scale;
}

// ---------- quantize w: 64x64 blocks -> fp8 (plain) + ws[nb][kb] ----------
__global__ __launch_bounds__(256) void quant_w_kernel(const float* __restrict__ w,
                                                      unsigned char* __restrict__ wq,
                                                      float* __restrict__ ws,
                                                      int N, int K) {
    const int nb = blockIdx.y, kb = blockIdx.x;
    const int KT = K >> 6;
    const int t = threadIdx.x;
    const int rgrp = t >> 4;
    const int cchk = t & 15;
    f32x4 v[4];
    float a = 0.0f;
#pragma unroll
    for (int i = 0; i < 4; ++i) {
        int row = nb * 64 + rgrp + i * 16;
        v[i] = *(const f32x4*)(w + (size_t)row * K + kb * 64 + cchk * 4);
        a = fmaxf(a, fmaxf(fmaxf(fabsf(v[i].x), fabsf(v[i].y)),
                           fmaxf(fabsf(v[i].z), fabsf(v[i].w))));
    }
#pragma unroll
    for (int off = 1; off < 64; off <<= 1) a = fmaxf(a, __shfl_xor(a, off));
    __shared__ float sm[4];
    if ((t & 63) == 0) sm[t >> 6] = a;
    __syncthreads();
    a = fmaxf(fmaxf(sm[0], sm[1]), fmaxf(sm[2], sm[3]));
    float scale = fmaxf(a, 1e-12f) / 448.0f;
#pragma unroll
    for (int i = 0; i < 4; ++i) {
        int row = nb * 64 + rgrp + i * 16;
        uchar4 o;
        o.x = enc_e4m3(v[i].x / scale);
        o.y = enc_e4m3(v[i].y / scale);
        o.z = enc_e4m3(v[i].z / scale);
        o.w = enc_e4m3(v[i].w / scale);
        *(uchar4*)(wq + (size_t)row * K + kb * 64 + cchk * 4) = o;
    }
    if (t == 0) ws[(size_t)nb * KT + kb] = scale;
}

// ---------- 256x256 block-scaled fp8 GEMM via mfma_scale_f32_32x32x64 ----------
// LDS: 64B rows, chunk c of row r at slot c ^ ((r>>1)&3)  [R9-verified: 0 conflicts,
// coalesced GLDS].  One 32x32x64 MFMA per fragment-pair covers all K=64.
// Unit e8m0 scales (0x7F = 2^0); per-tile arbitrary scales applied via VALU fmac.
#define GLDS(srcp, ldsp) __builtin_amdgcn_global_load_lds( \
    (__attribute__((address_space(1))) void*)(srcp),       \
    (__attribute__((address_space(3))) void*)(ldsp), 16, 0, 0)

__global__ __launch_bounds__(512, 2) void gemm_fp8(const unsigned char* __restrict__ Aq,
                                                   const unsigned char* __restrict__ Bq,
                                                   const float* __restrict__ xsT,
                                                   const float* __restrict__ wss,
                                                   const float* __restrict__ bias,
                                                   float* __restrict__ C,
                                                   int M, int N, int K) {
    __shared__ unsigned char Al[2][16384];    // X: 256 rows x 64B
    __shared__ unsigned char Bl[2][16384];    // W: 256 rows x 64B
    const int tid = threadIdx.x;
    const int wid = tid >> 6;
    const int lane = tid & 63;
    const int wm = wid >> 2, wn = wid & 3;    // 2(M) x 4(N), wave-tile 128x64
    const int l31 = lane & 31, h = lane >> 5;
    const int KT = K >> 6, NT = KT;

    // XCD-aware bijective swizzle (nwg = 512, %8==0)
    const int nbx = N >> 8;
    const int nwg = (M >> 8) * nbx;
    const int bid = blockIdx.x;
    const int swz = (bid & 7) * (nwg >> 3) + (bid >> 3);
    const int tm = swz / nbx, tn = swz % nbx;

    const unsigned char* gA = Aq + (size_t)tm * 256 * K;
    const unsigned char* gB = Bq + (size_t)tn * 256 * K;

    // staging source col swizzle (R9-identical): chunk = (lane&3) ^ ((lane>>3)&3)
    const int gswz = (((lane & 3) ^ ((lane >> 3) & 3)) << 4);

    // ds_read offsets: lane reads chunks {2h, 2h+1} of its row, slot = c ^ ((row>>1)&3)
    const int fsw = (l31 >> 1) & 3;
    const int slotLo = (2 * h) ^ fsw;
    const int oX = (wm * 128 + l31) * 64;
    const int oW = (wn * 64 + l31) * 64;
    const int oXlo = oX + slotLo * 16, oXhi = oX + (slotLo ^ 1) * 16;
    const int oWlo = oW + slotLo * 16, oWhi = oW + (slotLo ^ 1) * 16;

    const int iRow = tm * 256 + wm * 128 + l31;   // x-row (mi adds 32 each)
    const int jbw  = tn * 4 + wn;                 // W 64-block index

    const f32x16 z16 = {0.f,0.f,0.f,0.f,0.f,0.f,0.f,0.f,0.f,0.f,0.f,0.f,0.f,0.f,0.f,0.f};
    f32x16 macc[2][4];                             // [ni][mi]
#pragma unroll
    for (int n = 0; n < 2; ++n)
#pragma unroll
        for (int m = 0; m < 4; ++m) macc[n][m] = z16;

    i32x4 xlo[4], xhi[4], wlo[2], whi[2];
    float xsA[4], xsB[4], wsA = 0.f, wsB = 0.f, sarr[4];

    auto STG = [&](int t, int bufn) {              // 4 GLDS/wave (R9-identical)
#pragma unroll
        for (int i = 0; i < 2; ++i) {
            int seg = wid * 2 + i;                 // 16 segs x 1KB (16 rows) per operand
            int row = seg * 16 + (lane >> 2);
            GLDS(gA + (size_t)row * K + (size_t)t * 64 + gswz, (char*)&Al[bufn][0] + seg * 1024);
            GLDS(gB + (size_t)row * K + (size_t)t * 64 + gswz, (char*)&Bl[bufn][0] + seg * 1024);
        }
    };

    auto RD_X = [&](int buf, int mi) {
        xlo[mi] = *(const i32x4*)(&Al[buf][oXlo + mi * 2048]);
        xhi[mi] = *(const i32x4*)(&Al[buf][oXhi + mi * 2048]);
    };
    auto RD_W = [&](int buf, int ni) {
        wlo[ni] = *(const i32x4*)(&Bl[buf][oWlo + ni * 2048]);
        whi[ni] = *(const i32x4*)(&Bl[buf][oWhi + ni * 2048]);
    };

    // cluster: one ni x two mi; unit-scale K=64 MFMA then VALU rescale
    auto CL = [&](int ni, int mi0) {
        i32x8 wf = __builtin_shufflevector(wlo[ni], whi[ni], 0, 1, 2, 3, 4, 5, 6, 7);
#pragma unroll
        for (int q = 0; q < 2; ++q) {
            const int mi = mi0 + q;
            i32x8 xf = __builtin_shufflevector(xlo[mi], xhi[mi], 0, 1, 2, 3, 4, 5, 6, 7);
            f32x16 p = __builtin_amdgcn_mfma_scale_f32_32x32x64_f8f6f4(
                wf, xf, z16, 0, 0, 0, 0x7F7F7F7F, 0, 0x7F7F7F7F);
            macc[ni][mi] += p * sarr[mi];
        }
    };

    // prologue
    STG(0, 0);
#pragma unroll
    for (int m = 0; m < 4; ++m) xsA[m] = xsT[iRow + m * 32];
    wsA = wss[(size_t)jbw * KT];
    asm volatile("s_waitcnt vmcnt(0)" ::: "memory");
    asm volatile("s_barrier" ::: "memory");
    RD_W(0, 0); RD_X(0, 0); RD_X(0, 1);           // tail pattern: 6 ds_reads

    auto TILE = [&](int buf, int tnx, const float (&xsC)[4], float wsC,
                    float (&xsN)[4], float& wsN) {
        const int nb = buf ^ 1;
#pragma unroll
        for (int m = 0; m < 4; ++m) sarr[m] = xsC[m] * wsC;

        STG(tnx, nb);                              // next tile + its scales
#pragma unroll
        for (int m = 0; m < 4; ++m) xsN[m] = xsT[(size_t)tnx * M + iRow + m * 32];
        wsN = wss[(size_t)jbw * KT + tnx];

        RD_W(buf, 1);                              // 2 reads
        asm volatile("s_waitcnt lgkmcnt(2)" ::: "memory");
        __builtin_amdgcn_sched_barrier(0);
        __builtin_amdgcn_s_setprio(1);
        CL(0, 0);                                  // wf0 x xf0,1
        __builtin_amdgcn_s_setprio(0);

        RD_X(buf, 2); RD_X(buf, 3);                // 4 reads
        asm volatile("s_waitcnt lgkmcnt(4)" ::: "memory");
        __builtin_amdgcn_sched_barrier(0);
        __builtin_amdgcn_s_setprio(1);
        CL(1, 0);                                  // wf1 x xf0,1
        __builtin_amdgcn_s_setprio(0);

        asm volatile("s_waitcnt lgkmcnt(0)" ::: "memory");
        __builtin_amdgcn_sched_barrier(0);
        __builtin_amdgcn_s_setprio(1);
        CL(0, 2);                                  // wf0 x xf2,3
        CL(1, 2);                                  // wf1 x xf2,3
        __builtin_amdgcn_s_setprio(0);

        asm volatile("s_waitcnt vmcnt(0)" ::: "memory");   // next buf fully staged
        asm volatile("s_barrier" ::: "memory");            // join all waves
        RD_W(nb, 0); RD_X(nb, 0); RD_X(nb, 1);             // tail-read next tile
    };

    for (int t = 0; t < NT; t += 2) {
        int t1 = t + 1;
        int t2 = (t + 2 < NT) ? (t + 2) : 0;       // wrap: redundant but uniform
        TILE(0, t1, xsA, wsA, xsB, wsB);
        TILE(1, t2, xsB, wsB, xsA, wsA);
    }

    // epilogue: D col = lane&31 -> x-row i; D row = (reg&3)+8*(reg>>2)+4h -> w-col j
    const int i0 = tm * 256 + wm * 128 + l31;
    const int jn = tn * 256 + wn * 64 + 4 * h;
#pragma unroll
    for (int ni = 0; ni < 2; ++ni) {
#pragma unroll
        for (int mi = 0; mi < 4; ++mi) {
            const int row = i0 + mi * 32;
#pragma unroll
            for (int q = 0; q < 4; ++q) {
                const int col = jn + ni * 32 + 8 * q;
                f32x4 bv = *(const f32x4*)(bias + col);
                f32x4 vo;
#pragma unroll
                for (int j = 0; j < 4; ++j) {
                    unsigned short b = f32_to_bf16_bits(macc[ni][mi][q * 4 + j]);
                    vo[j] = __uint_as_float(((unsigned int)b) << 16) + bv[j];
                }
                *(f32x4*)(C + (size_t)row * N + col) = vo;
            }
        }
    }
}

extern "C" void kernel_launch(void* const* d_in, const int* in_sizes, int n_in,
                              void* d_out, int out_size, void* d_ws, size_t ws_size,
                              hipStream_t stream) {
    const float* x    = (const float*)d_in[0];
    const float* w    = (const float*)d_in[1];
    const float* bias = (const float*)d_in[2];
    float* out = (float*)d_out;

    const int N = in_sizes[2];
    const long long KL = (long long)in_sizes[1] / N;
    const int K = (int)KL;
    const int M = (int)((long long)in_sizes[0] / KL);
    const int KT = K / 64;

    unsigned char* xq = (unsigned char*)d_ws;                       // M*K fp8
    unsigned char* wq = xq + (size_t)M * K;                         // N*K fp8
    float* xsT = (float*)(wq + (size_t)N * K);                      // KT*M f32
    float* wss = xsT + (size_t)KT * M;                              // (N/64)*KT f32

    long long n4 = (long long)M * K / 4;
    quant_x_kernel<<<(unsigned)((n4 + 255) / 256), 256, 0, stream>>>(x, xq, xsT, n4, K, M);

    dim3 gw(K / 64, N / 64);
    quant_w_kernel<<<gw, 256, 0, stream>>>(w, wq, wss, N, K);

    const int nwg = (M / 256) * (N / 256);
    gemm_fp8<<<nwg, 512, 0, stream>>>(xq, wq, xsT, wss, bias, out, M, N, K);
}